// Round 2
// baseline (590.144 us; speedup 1.0000x reference)
//
#include <hip/hip_runtime.h>
#include <hip/hip_cooperative_groups.h>
#include <math.h>

namespace cg = cooperative_groups;

#define NUM_CLASSES 10
#define BLOCKS 1024   // 4 blocks/CU x 256 CU -> exactly co-resident for cooperative launch
#define TPB 256

// ws layout (every used word overwritten each call; no memset, no atomics):
//   [0)     unsigned pc[BLOCKS][NUM_CLASSES]  per-block histograms (40960 B)
//   [40960) float2   pacc[BLOCKS]             per-block partials    (8192 B)
//
// R1 post-mortem: wave-private LDS transpose of the stream loop was exactly
// neutral -> main was already at its BW floor with direct 80-B-stride loads.
// Remaining controllable cost is dispatch overhead: fuse hist/main/finalize
// into ONE cooperative kernel (2 grid.sync()s), direct loads, no LDS staging.

__device__ __forceinline__ void compute_pair(const float4 r[5], const float w[NUM_CLASSES],
                                             float& sum_log, float& sumsq) {
    float r0[NUM_CLASSES] = {r[0].x, r[0].y, r[0].z, r[0].w,
                             r[1].x, r[1].y, r[1].z, r[1].w, r[2].x, r[2].y};
    float r1[NUM_CLASSES] = {r[2].z, r[2].w, r[3].x, r[3].y,
                             r[3].z, r[3].w, r[4].x, r[4].y, r[4].z, r[4].w};
    float nom0 = 0.f, nom1 = 0.f;
#pragma unroll
    for (int c = 0; c < NUM_CLASSES; ++c) {
        nom0 += r0[c] * w[c];
        nom1 += r1[c] * w[c];
        sumsq += r0[c] * r0[c] + r1[c] * r1[c];
    }
    sum_log += __logf(nom0) + __logf(nom1);
}

__device__ __forceinline__ void process_pair(const float4* __restrict__ o4, size_t p,
                                             const float w[NUM_CLASSES],
                                             float& sum_log, float& sumsq) {
    const float4* base = o4 + p * 5;  // 2 rows = 20 floats = 5 aligned float4
    float4 r[5] = {base[0], base[1], base[2], base[3], base[4]};
    compute_pair(r, w, sum_log, sumsq);
}

__global__ void __launch_bounds__(TPB, 4) fused_kernel(const float* __restrict__ outputs,
                                                       const int* __restrict__ target,
                                                       unsigned int* __restrict__ pc,
                                                       float2* __restrict__ pacc,
                                                       float* __restrict__ out, int n) {
    const int wave = threadIdx.x >> 6;
    const int lane = threadIdx.x & 63;
    const int tid = blockIdx.x * blockDim.x + threadIdx.x;
    const int nthreads = gridDim.x * blockDim.x;  // 262144

    __shared__ unsigned int shw[4][NUM_CLASSES];
    __shared__ float fw[NUM_CLASSES];
    __shared__ float s1[4], s2[4];

    // ---- phase A: histogram of targets -> pc[blockIdx.x] ----
    // Packed 6-bit-per-class counter: 10 classes * 6 bits = 60 bits.
    // Flush every 8 int4 (32 elems) -> per-class count <= 32 < 63 cap.
    unsigned int cnt[NUM_CLASSES];
#pragma unroll
    for (int c = 0; c < NUM_CLASSES; ++c) cnt[c] = 0u;
    {
        const int4* __restrict__ t4 = (const int4*)target;  // harness passes int32 targets
        const int n4 = n >> 2;
        unsigned long long acc = 0ull;
        int pend = 0;
        for (int i = tid; i < n4; i += nthreads) {
            int4 v = t4[i];
            acc += (1ull << (6 * v.x)) + (1ull << (6 * v.y)) +
                   (1ull << (6 * v.z)) + (1ull << (6 * v.w));
            if (++pend == 8) {
#pragma unroll
                for (int c = 0; c < NUM_CLASSES; ++c)
                    cnt[c] += (unsigned int)((acc >> (6 * c)) & 63ull);
                acc = 0ull;
                pend = 0;
            }
        }
#pragma unroll
        for (int c = 0; c < NUM_CLASSES; ++c)
            cnt[c] += (unsigned int)((acc >> (6 * c)) & 63ull);
    }
#pragma unroll
    for (int c = 0; c < NUM_CLASSES; ++c) {
        unsigned int v = cnt[c];
        for (int off = 32; off > 0; off >>= 1)
            v += (unsigned int)__shfl_down((int)v, off, 64);
        cnt[c] = v;
    }
    if (lane == 0) {
#pragma unroll
        for (int c = 0; c < NUM_CLASSES; ++c) shw[wave][c] = cnt[c];
    }
    __syncthreads();
    if (threadIdx.x < NUM_CLASSES) {
        const int c = threadIdx.x;
        pc[blockIdx.x * NUM_CLASSES + c] = shw[0][c] + shw[1][c] + shw[2][c] + shw[3][c];
    }
    __threadfence();            // make pc visible device-wide (cross-XCD)
    cg::this_grid().sync();

    // ---- phase B1: reduce per-block histograms -> w[10] (block-local) ----
    unsigned int pw[NUM_CLASSES];
#pragma unroll
    for (int c = 0; c < NUM_CLASSES; ++c) pw[c] = 0u;
#pragma unroll
    for (int r = 0; r < BLOCKS / TPB; ++r) {
        const unsigned int* row = pc + (threadIdx.x + r * TPB) * NUM_CLASSES;
#pragma unroll
        for (int c = 0; c < NUM_CLASSES; ++c) pw[c] += row[c];
    }
#pragma unroll
    for (int c = 0; c < NUM_CLASSES; ++c) {
        unsigned int v = pw[c];
        for (int off = 32; off > 0; off >>= 1)
            v += (unsigned int)__shfl_down((int)v, off, 64);
        pw[c] = v;
    }
    if (lane == 0) {
#pragma unroll
        for (int c = 0; c < NUM_CLASSES; ++c) shw[wave][c] = pw[c];
    }
    __syncthreads();
    if (threadIdx.x < NUM_CLASSES) {
        const int c = threadIdx.x;
        fw[c] = (float)(shw[0][c] + shw[1][c] + shw[2][c] + shw[3][c]);
    }
    __syncthreads();
    float w[NUM_CLASSES];
#pragma unroll
    for (int c = 0; c < NUM_CLASSES; ++c) w[c] = fw[c];

    // ---- phase B2: direct-load stream, barrier-free, 2x unrolled for ILP ----
    const float4* __restrict__ o4 = (const float4*)outputs;
    const int npairs = n >> 1;  // 2^21 -> exactly 8 pairs/thread
    float sum_log = 0.f, sumsq = 0.f;
    for (int p = tid; p < npairs; p += 2 * nthreads) {
        process_pair(o4, (size_t)p, w, sum_log, sumsq);
        const int p2 = p + nthreads;
        if (p2 < npairs) process_pair(o4, (size_t)p2, w, sum_log, sumsq);
    }

    // ---- phase B3: block reduce -> pacc[blockIdx.x] ----
    for (int off = 32; off > 0; off >>= 1) {
        sum_log += __shfl_down(sum_log, off, 64);
        sumsq += __shfl_down(sumsq, off, 64);
    }
    if (lane == 0) { s1[wave] = sum_log; s2[wave] = sumsq; }
    __syncthreads();
    if (threadIdx.x == 0) {
        pacc[blockIdx.x] = make_float2(s1[0] + s1[1] + s1[2] + s1[3],
                                       s2[0] + s2[1] + s2[2] + s2[3]);
    }
    __threadfence();            // make pacc visible device-wide (cross-XCD)
    cg::this_grid().sync();

    // ---- phase C: block 0 finalizes ----
    if (blockIdx.x == 0) {
        float t1 = 0.f, t2 = 0.f;
        for (int i = threadIdx.x; i < BLOCKS; i += TPB) {
            float2 v = pacc[i];
            t1 += v.x;
            t2 += v.y;
        }
        for (int off = 32; off > 0; off >>= 1) {
            t1 += __shfl_down(t1, off, 64);
            t2 += __shfl_down(t2, off, 64);
        }
        if (lane == 0) { s1[wave] = t1; s2[wave] = t2; }
        __syncthreads();
        if (threadIdx.x == 0) {
            const float fn = (float)n;
            float a = s1[0] + s1[1] + s1[2] + s1[3];
            float b = s2[0] + s2[1] + s2[2] + s2[3];
            // mean(-log(nom/denom)) = 0.5*log(sumsq) + 0.5*log(N) - sum_log/N
            out[0] = 0.5f * logf(b) + 0.5f * logf(fn) - a / fn;
        }
    }
}

extern "C" void kernel_launch(void* const* d_in, const int* in_sizes, int n_in,
                              void* d_out, int out_size, void* d_ws, size_t ws_size,
                              hipStream_t stream) {
    const float* outputs = (const float*)d_in[0];
    const int* target = (const int*)d_in[1];
    int n = in_sizes[1];

    unsigned int* pc = (unsigned int*)d_ws;
    float2* pacc = (float2*)((char*)d_ws + 40960);
    float* outp = (float*)d_out;

    void* args[] = {(void*)&outputs, (void*)&target, (void*)&pc,
                    (void*)&pacc,    (void*)&outp,   (void*)&n};
    hipLaunchCooperativeKernel((const void*)fused_kernel, dim3(BLOCKS), dim3(TPB),
                               args, 0, stream);
}

// Round 4
// 358.591 us; speedup vs baseline: 1.6457x; 1.6457x over previous
//
#include <hip/hip_runtime.h>
#include <math.h>

#define NUM_CLASSES 10
#define A_BLOCKS 512
#define B_BLOCKS 2048

typedef __attribute__((ext_vector_type(4))) float f32x4;  // clang-native: ok for nontemporal builtin

// ws layout (every used word overwritten each call; no memset needed):
//   [0)     unsigned pc[A_BLOCKS][NUM_CLASSES]  per-block histograms (20480 B)
//   [20480) float2   pacc[B_BLOCKS]             per-block partials   (16384 B)
//   [36864) unsigned ticket                     last-block counter   (4 B; zeroed by hist)
//
// R2 post-mortem: cg::grid().sync() costs ~185 us/sync at 1024 blocks (two
// syncs -> 405 us kernel). Grid barriers are banned for this part; phase
// dependencies stay as separate dispatches. This version is the proven
// 3-dispatch R0 structure minus the finalize dispatch (folded into the LAST
// main block via an atomic ticket -- one-way dependency, no spinning) plus
// nontemporal loads on the write-once-read-once outputs stream.
// R3 fix: __builtin_nontemporal_load needs a clang-native vector type, not
// HIP_vector_type float4 -> load through f32x4.

__global__ void __launch_bounds__(256) hist_kernel(const int* __restrict__ target,
                                                   unsigned int* __restrict__ pc,
                                                   unsigned int* __restrict__ ticket, int n) {
    // zero the ticket for main_kernel (ws is poison-filled each call)
    if (blockIdx.x == 0 && threadIdx.x == 0) *ticket = 0u;

    unsigned int cnt[NUM_CLASSES];
#pragma unroll
    for (int c = 0; c < NUM_CLASSES; ++c) cnt[c] = 0u;

    const int tid = blockIdx.x * blockDim.x + threadIdx.x;
    const int stride = gridDim.x * blockDim.x;
    const int4* __restrict__ t4 = (const int4*)target;  // harness passes int32 targets
    const int n4 = n >> 2;

    // Packed 6-bit-per-class counter: flush every 8 int4 (32 elems) < 63 cap.
    unsigned long long acc = 0ull;
    int pend = 0;
    for (int i = tid; i < n4; i += stride) {
        int4 v = t4[i];
        acc += (1ull << (6 * v.x)) + (1ull << (6 * v.y)) +
               (1ull << (6 * v.z)) + (1ull << (6 * v.w));
        if (++pend == 8) {
#pragma unroll
            for (int c = 0; c < NUM_CLASSES; ++c)
                cnt[c] += (unsigned int)((acc >> (6 * c)) & 63ull);
            acc = 0ull;
            pend = 0;
        }
    }
#pragma unroll
    for (int c = 0; c < NUM_CLASSES; ++c)
        cnt[c] += (unsigned int)((acc >> (6 * c)) & 63ull);

#pragma unroll
    for (int c = 0; c < NUM_CLASSES; ++c) {
        unsigned int v = cnt[c];
        for (int off = 32; off > 0; off >>= 1)
            v += (unsigned int)__shfl_down((int)v, off, 64);
        cnt[c] = v;
    }

    __shared__ unsigned int sh[4][NUM_CLASSES];
    const int wave = threadIdx.x >> 6;
    if ((threadIdx.x & 63) == 0) {
#pragma unroll
        for (int c = 0; c < NUM_CLASSES; ++c) sh[wave][c] = cnt[c];
    }
    __syncthreads();
    if (threadIdx.x < NUM_CLASSES) {
        const int c = threadIdx.x;
        pc[blockIdx.x * NUM_CLASSES + c] = sh[0][c] + sh[1][c] + sh[2][c] + sh[3][c];
    }
}

__device__ __forceinline__ void process_pair(const f32x4* __restrict__ o4, size_t p,
                                             const float w[NUM_CLASSES],
                                             float& sum_log, float& sumsq) {
    const f32x4* base = o4 + p * 5;  // 2 rows = 20 floats = 5 aligned float4
    f32x4 a = __builtin_nontemporal_load(base + 0);
    f32x4 b = __builtin_nontemporal_load(base + 1);
    f32x4 c4 = __builtin_nontemporal_load(base + 2);
    f32x4 d = __builtin_nontemporal_load(base + 3);
    f32x4 e = __builtin_nontemporal_load(base + 4);
    float r0[NUM_CLASSES] = {a.x, a.y, a.z, a.w, b.x, b.y, b.z, b.w, c4.x, c4.y};
    float r1[NUM_CLASSES] = {c4.z, c4.w, d.x, d.y, d.z, d.w, e.x, e.y, e.z, e.w};
    float nom0 = 0.f, nom1 = 0.f;
#pragma unroll
    for (int c = 0; c < NUM_CLASSES; ++c) {
        nom0 += r0[c] * w[c];
        nom1 += r1[c] * w[c];
        sumsq += r0[c] * r0[c] + r1[c] * r1[c];
    }
    sum_log += __logf(nom0) + __logf(nom1);
}

__global__ void __launch_bounds__(256) main_kernel(const float* __restrict__ outputs,
                                                   const unsigned int* __restrict__ pc,
                                                   float2* __restrict__ pacc,
                                                   unsigned int* __restrict__ ticket,
                                                   float* __restrict__ out, int n) {
    const int wave = threadIdx.x >> 6;
    const int lane = threadIdx.x & 63;

    // ---- phase 1: reduce per-block histograms -> w[10] (block-local) ----
    unsigned int pw[NUM_CLASSES];
#pragma unroll
    for (int c = 0; c < NUM_CLASSES; ++c) pw[c] = 0u;
#pragma unroll
    for (int r = 0; r < A_BLOCKS / 256; ++r) {
        const unsigned int* row = pc + (threadIdx.x + r * 256) * NUM_CLASSES;
#pragma unroll
        for (int c = 0; c < NUM_CLASSES; ++c) pw[c] += row[c];
    }
#pragma unroll
    for (int c = 0; c < NUM_CLASSES; ++c) {
        unsigned int v = pw[c];
        for (int off = 32; off > 0; off >>= 1)
            v += (unsigned int)__shfl_down((int)v, off, 64);
        pw[c] = v;
    }
    __shared__ unsigned int shw[4][NUM_CLASSES];
    __shared__ float fw[NUM_CLASSES];
    if (lane == 0) {
#pragma unroll
        for (int c = 0; c < NUM_CLASSES; ++c) shw[wave][c] = pw[c];
    }
    __syncthreads();
    if (threadIdx.x < NUM_CLASSES) {
        const int c = threadIdx.x;
        fw[c] = (float)(shw[0][c] + shw[1][c] + shw[2][c] + shw[3][c]);
    }
    __syncthreads();
    float w[NUM_CLASSES];
#pragma unroll
    for (int c = 0; c < NUM_CLASSES; ++c) w[c] = fw[c];

    // ---- phase 2: direct-load stream, barrier-free, 2x unrolled for ILP ----
    const f32x4* __restrict__ o4 = (const f32x4*)outputs;
    const int npairs = n >> 1;                    // 2^21
    const int stride = gridDim.x * blockDim.x;    // 524288 -> exactly 4 pairs/thread
    const int tid = blockIdx.x * blockDim.x + threadIdx.x;

    float sum_log = 0.f, sumsq = 0.f;
    for (int p = tid; p < npairs; p += 2 * stride) {
        process_pair(o4, (size_t)p, w, sum_log, sumsq);
        const int p2 = p + stride;
        if (p2 < npairs) process_pair(o4, (size_t)p2, w, sum_log, sumsq);
    }

    // ---- phase 3: block reduce, store per-block partial ----
    for (int off = 32; off > 0; off >>= 1) {
        sum_log += __shfl_down(sum_log, off, 64);
        sumsq += __shfl_down(sumsq, off, 64);
    }
    __shared__ float s1[4], s2[4];
    __shared__ int is_last;
    if (lane == 0) { s1[wave] = sum_log; s2[wave] = sumsq; }
    __syncthreads();
    if (threadIdx.x == 0) {
        pacc[blockIdx.x] = make_float2(s1[0] + s1[1] + s1[2] + s1[3],
                                       s2[0] + s2[1] + s2[2] + s2[3]);
        __threadfence();  // release: pacc store visible before ticket bump
        unsigned int old = atomicAdd(ticket, 1u);
        is_last = (old == (unsigned int)(gridDim.x - 1)) ? 1 : 0;
    }
    __syncthreads();

    // ---- phase 4: LAST block folds the finalize (no extra dispatch) ----
    if (is_last) {
        __threadfence();  // acquire: all other blocks' pacc stores now visible
        const volatile float* pv = (const volatile float*)pacc;
        float t1 = 0.f, t2 = 0.f;
        for (int i = threadIdx.x; i < B_BLOCKS; i += 256) {
            t1 += pv[2 * i];
            t2 += pv[2 * i + 1];
        }
        for (int off = 32; off > 0; off >>= 1) {
            t1 += __shfl_down(t1, off, 64);
            t2 += __shfl_down(t2, off, 64);
        }
        if (lane == 0) { s1[wave] = t1; s2[wave] = t2; }
        __syncthreads();
        if (threadIdx.x == 0) {
            const float fn = (float)n;
            float a = s1[0] + s1[1] + s1[2] + s1[3];
            float b = s2[0] + s2[1] + s2[2] + s2[3];
            // mean(-log(nom/denom)) = 0.5*log(sumsq) + 0.5*log(N) - sum_log/N
            out[0] = 0.5f * logf(b) + 0.5f * logf(fn) - a / fn;
        }
    }
}

extern "C" void kernel_launch(void* const* d_in, const int* in_sizes, int n_in,
                              void* d_out, int out_size, void* d_ws, size_t ws_size,
                              hipStream_t stream) {
    const float* outputs = (const float*)d_in[0];
    const int* target = (const int*)d_in[1];
    const int n = in_sizes[1];

    unsigned int* pc = (unsigned int*)d_ws;
    float2* pacc = (float2*)((char*)d_ws + 20480);
    unsigned int* ticket = (unsigned int*)((char*)d_ws + 36864);

    hist_kernel<<<A_BLOCKS, 256, 0, stream>>>(target, pc, ticket, n);
    main_kernel<<<B_BLOCKS, 256, 0, stream>>>(outputs, pc, pacc, ticket, (float*)d_out, n);
}

// Round 5
// 350.647 us; speedup vs baseline: 1.6830x; 1.0227x over previous
//
#include <hip/hip_runtime.h>
#include <math.h>

#define NUM_CLASSES 10
#define A_BLOCKS 512
#define B_BLOCKS 2048

// ws layout (every used word overwritten each call; no memset needed):
//   [0)     unsigned pc[A_BLOCKS][NUM_CLASSES]  per-block histograms (20480 B)
//   [20480) float2   pacc[B_BLOCKS]             per-block partials   (16384 B)
//   [36864) unsigned ticket                     last-block counter   (4 B; zeroed by hist)
//
// R2 post-mortem: cg::grid().sync() ~185 us/sync at 1024 blocks -> grid
// barriers banned; phase deps stay as separate dispatches.
// R4 post-mortem: __builtin_nontemporal_load on the hot stream cost 4x
// (main 46 -> 165 us) on gfx950 -> plain float4 loads only. Ticket-fold of
// the finalize dispatch is kept (2048 staggered memory-side atomics, ~us).
// New: fully-unrolled fast path (npairs == 4*stride exactly) issues all 20
// dwordx4 loads per thread up front for max outstanding loads.

__global__ void __launch_bounds__(256) hist_kernel(const int* __restrict__ target,
                                                   unsigned int* __restrict__ pc,
                                                   unsigned int* __restrict__ ticket, int n) {
    // zero the ticket for main_kernel (ws is poison-filled each call)
    if (blockIdx.x == 0 && threadIdx.x == 0) *ticket = 0u;

    unsigned int cnt[NUM_CLASSES];
#pragma unroll
    for (int c = 0; c < NUM_CLASSES; ++c) cnt[c] = 0u;

    const int tid = blockIdx.x * blockDim.x + threadIdx.x;
    const int stride = gridDim.x * blockDim.x;
    const int4* __restrict__ t4 = (const int4*)target;  // harness passes int32 targets
    const int n4 = n >> 2;

    // Packed 6-bit-per-class counter: flush every 8 int4 (32 elems) < 63 cap.
    unsigned long long acc = 0ull;
    int pend = 0;
    for (int i = tid; i < n4; i += stride) {
        int4 v = t4[i];
        acc += (1ull << (6 * v.x)) + (1ull << (6 * v.y)) +
               (1ull << (6 * v.z)) + (1ull << (6 * v.w));
        if (++pend == 8) {
#pragma unroll
            for (int c = 0; c < NUM_CLASSES; ++c)
                cnt[c] += (unsigned int)((acc >> (6 * c)) & 63ull);
            acc = 0ull;
            pend = 0;
        }
    }
#pragma unroll
    for (int c = 0; c < NUM_CLASSES; ++c)
        cnt[c] += (unsigned int)((acc >> (6 * c)) & 63ull);

#pragma unroll
    for (int c = 0; c < NUM_CLASSES; ++c) {
        unsigned int v = cnt[c];
        for (int off = 32; off > 0; off >>= 1)
            v += (unsigned int)__shfl_down((int)v, off, 64);
        cnt[c] = v;
    }

    __shared__ unsigned int sh[4][NUM_CLASSES];
    const int wave = threadIdx.x >> 6;
    if ((threadIdx.x & 63) == 0) {
#pragma unroll
        for (int c = 0; c < NUM_CLASSES; ++c) sh[wave][c] = cnt[c];
    }
    __syncthreads();
    if (threadIdx.x < NUM_CLASSES) {
        const int c = threadIdx.x;
        pc[blockIdx.x * NUM_CLASSES + c] = sh[0][c] + sh[1][c] + sh[2][c] + sh[3][c];
    }
}

__device__ __forceinline__ void compute_from(const float4 a, const float4 b, const float4 c4,
                                             const float4 d, const float4 e,
                                             const float w[NUM_CLASSES],
                                             float& sum_log, float& sumsq) {
    float r0[NUM_CLASSES] = {a.x, a.y, a.z, a.w, b.x, b.y, b.z, b.w, c4.x, c4.y};
    float r1[NUM_CLASSES] = {c4.z, c4.w, d.x, d.y, d.z, d.w, e.x, e.y, e.z, e.w};
    float nom0 = 0.f, nom1 = 0.f;
#pragma unroll
    for (int c = 0; c < NUM_CLASSES; ++c) {
        nom0 += r0[c] * w[c];
        nom1 += r1[c] * w[c];
        sumsq += r0[c] * r0[c] + r1[c] * r1[c];
    }
    sum_log += __logf(nom0) + __logf(nom1);
}

__device__ __forceinline__ void process_pair(const float4* __restrict__ o4, size_t p,
                                             const float w[NUM_CLASSES],
                                             float& sum_log, float& sumsq) {
    const float4* base = o4 + p * 5;  // 2 rows = 20 floats = 5 aligned float4
    compute_from(base[0], base[1], base[2], base[3], base[4], w, sum_log, sumsq);
}

__global__ void __launch_bounds__(256) main_kernel(const float* __restrict__ outputs,
                                                   const unsigned int* __restrict__ pc,
                                                   float2* __restrict__ pacc,
                                                   unsigned int* __restrict__ ticket,
                                                   float* __restrict__ out, int n) {
    const int wave = threadIdx.x >> 6;
    const int lane = threadIdx.x & 63;

    // ---- phase 1: reduce per-block histograms -> w[10] (block-local) ----
    unsigned int pw[NUM_CLASSES];
#pragma unroll
    for (int c = 0; c < NUM_CLASSES; ++c) pw[c] = 0u;
#pragma unroll
    for (int r = 0; r < A_BLOCKS / 256; ++r) {
        const unsigned int* row = pc + (threadIdx.x + r * 256) * NUM_CLASSES;
#pragma unroll
        for (int c = 0; c < NUM_CLASSES; ++c) pw[c] += row[c];
    }
#pragma unroll
    for (int c = 0; c < NUM_CLASSES; ++c) {
        unsigned int v = pw[c];
        for (int off = 32; off > 0; off >>= 1)
            v += (unsigned int)__shfl_down((int)v, off, 64);
        pw[c] = v;
    }
    __shared__ unsigned int shw[4][NUM_CLASSES];
    __shared__ float fw[NUM_CLASSES];
    if (lane == 0) {
#pragma unroll
        for (int c = 0; c < NUM_CLASSES; ++c) shw[wave][c] = pw[c];
    }
    __syncthreads();
    if (threadIdx.x < NUM_CLASSES) {
        const int c = threadIdx.x;
        fw[c] = (float)(shw[0][c] + shw[1][c] + shw[2][c] + shw[3][c]);
    }
    __syncthreads();
    float w[NUM_CLASSES];
#pragma unroll
    for (int c = 0; c < NUM_CLASSES; ++c) w[c] = fw[c];

    // ---- phase 2: direct-load stream, barrier-free ----
    const float4* __restrict__ o4 = (const float4*)outputs;
    const int npairs = n >> 1;                    // 2^21
    const int stride = gridDim.x * blockDim.x;    // 524288 -> exactly 4 pairs/thread
    const int tid = blockIdx.x * blockDim.x + threadIdx.x;

    float sum_log = 0.f, sumsq = 0.f;
    if (npairs == 4 * stride) {
        // fast path: issue all 20 dwordx4 loads up front, then compute
        const float4* b0 = o4 + (size_t)(tid + 0 * stride) * 5;
        const float4* b1 = o4 + (size_t)(tid + 1 * stride) * 5;
        const float4* b2 = o4 + (size_t)(tid + 2 * stride) * 5;
        const float4* b3 = o4 + (size_t)(tid + 3 * stride) * 5;
        float4 g[20];
#pragma unroll
        for (int k = 0; k < 5; ++k) g[0 + k] = b0[k];
#pragma unroll
        for (int k = 0; k < 5; ++k) g[5 + k] = b1[k];
#pragma unroll
        for (int k = 0; k < 5; ++k) g[10 + k] = b2[k];
#pragma unroll
        for (int k = 0; k < 5; ++k) g[15 + k] = b3[k];
#pragma unroll
        for (int q = 0; q < 4; ++q)
            compute_from(g[5 * q], g[5 * q + 1], g[5 * q + 2], g[5 * q + 3], g[5 * q + 4],
                         w, sum_log, sumsq);
    } else {
        for (int p = tid; p < npairs; p += 2 * stride) {
            process_pair(o4, (size_t)p, w, sum_log, sumsq);
            const int p2 = p + stride;
            if (p2 < npairs) process_pair(o4, (size_t)p2, w, sum_log, sumsq);
        }
    }

    // ---- phase 3: block reduce, store per-block partial ----
    for (int off = 32; off > 0; off >>= 1) {
        sum_log += __shfl_down(sum_log, off, 64);
        sumsq += __shfl_down(sumsq, off, 64);
    }
    __shared__ float s1[4], s2[4];
    __shared__ int is_last;
    if (lane == 0) { s1[wave] = sum_log; s2[wave] = sumsq; }
    __syncthreads();
    if (threadIdx.x == 0) {
        pacc[blockIdx.x] = make_float2(s1[0] + s1[1] + s1[2] + s1[3],
                                       s2[0] + s2[1] + s2[2] + s2[3]);
        __threadfence();  // release: pacc store visible before ticket bump
        unsigned int old = atomicAdd(ticket, 1u);
        is_last = (old == (unsigned int)(gridDim.x - 1)) ? 1 : 0;
    }
    __syncthreads();

    // ---- phase 4: LAST block folds the finalize (no extra dispatch) ----
    if (is_last) {
        __threadfence();  // acquire: all other blocks' pacc stores now visible
        const volatile float* pv = (const volatile float*)pacc;
        float t1 = 0.f, t2 = 0.f;
        for (int i = threadIdx.x; i < B_BLOCKS; i += 256) {
            t1 += pv[2 * i];
            t2 += pv[2 * i + 1];
        }
        for (int off = 32; off > 0; off >>= 1) {
            t1 += __shfl_down(t1, off, 64);
            t2 += __shfl_down(t2, off, 64);
        }
        if (lane == 0) { s1[wave] = t1; s2[wave] = t2; }
        __syncthreads();
        if (threadIdx.x == 0) {
            const float fn = (float)n;
            float a = s1[0] + s1[1] + s1[2] + s1[3];
            float b = s2[0] + s2[1] + s2[2] + s2[3];
            // mean(-log(nom/denom)) = 0.5*log(sumsq) + 0.5*log(N) - sum_log/N
            out[0] = 0.5f * logf(b) + 0.5f * logf(fn) - a / fn;
        }
    }
}

extern "C" void kernel_launch(void* const* d_in, const int* in_sizes, int n_in,
                              void* d_out, int out_size, void* d_ws, size_t ws_size,
                              hipStream_t stream) {
    const float* outputs = (const float*)d_in[0];
    const int* target = (const int*)d_in[1];
    const int n = in_sizes[1];

    unsigned int* pc = (unsigned int*)d_ws;
    float2* pacc = (float2*)((char*)d_ws + 20480);
    unsigned int* ticket = (unsigned int*)((char*)d_ws + 36864);

    hist_kernel<<<A_BLOCKS, 256, 0, stream>>>(target, pc, ticket, n);
    main_kernel<<<B_BLOCKS, 256, 0, stream>>>(outputs, pc, pacc, ticket, (float*)d_out, n);
}

// Round 6
// 247.506 us; speedup vs baseline: 2.3844x; 1.4167x over previous
//
#include <hip/hip_runtime.h>
#include <math.h>

#define NUM_CLASSES 10
#define A_BLOCKS 512
#define B_BLOCKS 2048

// ws layout (every used word overwritten each call; no memset, no atomics):
//   [0)     unsigned pc[A_BLOCKS][NUM_CLASSES]  per-block histograms (20480 B)
//   [20480) float2   pacc[B_BLOCKS]             per-block partials   (16384 B)
//
// Session ledger:
//  R1: wave-private LDS transpose (perfect coalescing) -> exactly neutral.
//      Stream is NOT request/coalescing-limited.
//  R2: cg::grid().sync() ~185 us/sync at 1024 blocks. Grid barriers banned.
//  R4/R5: per-block __threadfence (agent-scope release -> buffer_wbl2 on
//      non-coherent per-XCD L2) + ticket atomic cost ~+125 us, independent
//      of data locality (R5 replay: 174 us at FETCH=131 KB). Per-block
//      device-scope fences banned. nt loads were innocent but unhelpful.
//  => Phase deps stay as 3 separate dispatches (proven 248 us structure).
//  R6 (this): single isolated change -- stream fast path issues all 20
//      dwordx4 loads up front, pinned with sched_barrier(0).

__global__ void __launch_bounds__(256) hist_kernel(const int* __restrict__ target,
                                                   unsigned int* __restrict__ pc, int n) {
    unsigned int cnt[NUM_CLASSES];
#pragma unroll
    for (int c = 0; c < NUM_CLASSES; ++c) cnt[c] = 0u;

    const int tid = blockIdx.x * blockDim.x + threadIdx.x;
    const int stride = gridDim.x * blockDim.x;
    const int4* __restrict__ t4 = (const int4*)target;  // harness passes int32 targets
    const int n4 = n >> 2;

    // Packed 6-bit-per-class counter: flush every 8 int4 (32 elems) < 63 cap.
    unsigned long long acc = 0ull;
    int pend = 0;
    for (int i = tid; i < n4; i += stride) {
        int4 v = t4[i];
        acc += (1ull << (6 * v.x)) + (1ull << (6 * v.y)) +
               (1ull << (6 * v.z)) + (1ull << (6 * v.w));
        if (++pend == 8) {
#pragma unroll
            for (int c = 0; c < NUM_CLASSES; ++c)
                cnt[c] += (unsigned int)((acc >> (6 * c)) & 63ull);
            acc = 0ull;
            pend = 0;
        }
    }
#pragma unroll
    for (int c = 0; c < NUM_CLASSES; ++c)
        cnt[c] += (unsigned int)((acc >> (6 * c)) & 63ull);

#pragma unroll
    for (int c = 0; c < NUM_CLASSES; ++c) {
        unsigned int v = cnt[c];
        for (int off = 32; off > 0; off >>= 1)
            v += (unsigned int)__shfl_down((int)v, off, 64);
        cnt[c] = v;
    }

    __shared__ unsigned int sh[4][NUM_CLASSES];
    const int wave = threadIdx.x >> 6;
    if ((threadIdx.x & 63) == 0) {
#pragma unroll
        for (int c = 0; c < NUM_CLASSES; ++c) sh[wave][c] = cnt[c];
    }
    __syncthreads();
    if (threadIdx.x < NUM_CLASSES) {
        const int c = threadIdx.x;
        pc[blockIdx.x * NUM_CLASSES + c] = sh[0][c] + sh[1][c] + sh[2][c] + sh[3][c];
    }
}

__device__ __forceinline__ void compute_from(const float4 a, const float4 b, const float4 c4,
                                             const float4 d, const float4 e,
                                             const float w[NUM_CLASSES],
                                             float& sum_log, float& sumsq) {
    float r0[NUM_CLASSES] = {a.x, a.y, a.z, a.w, b.x, b.y, b.z, b.w, c4.x, c4.y};
    float r1[NUM_CLASSES] = {c4.z, c4.w, d.x, d.y, d.z, d.w, e.x, e.y, e.z, e.w};
    float nom0 = 0.f, nom1 = 0.f;
#pragma unroll
    for (int c = 0; c < NUM_CLASSES; ++c) {
        nom0 += r0[c] * w[c];
        nom1 += r1[c] * w[c];
        sumsq += r0[c] * r0[c] + r1[c] * r1[c];
    }
    sum_log += __logf(nom0) + __logf(nom1);
}

__device__ __forceinline__ void process_pair(const float4* __restrict__ o4, size_t p,
                                             const float w[NUM_CLASSES],
                                             float& sum_log, float& sumsq) {
    const float4* base = o4 + p * 5;  // 2 rows = 20 floats = 5 aligned float4
    compute_from(base[0], base[1], base[2], base[3], base[4], w, sum_log, sumsq);
}

__global__ void __launch_bounds__(256) main_kernel(const float* __restrict__ outputs,
                                                   const unsigned int* __restrict__ pc,
                                                   float2* __restrict__ pacc, int n) {
    const int wave = threadIdx.x >> 6;
    const int lane = threadIdx.x & 63;

    // ---- phase 1: reduce per-block histograms -> w[10] (block-local) ----
    unsigned int pw[NUM_CLASSES];
#pragma unroll
    for (int c = 0; c < NUM_CLASSES; ++c) pw[c] = 0u;
#pragma unroll
    for (int r = 0; r < A_BLOCKS / 256; ++r) {
        const unsigned int* row = pc + (threadIdx.x + r * 256) * NUM_CLASSES;
#pragma unroll
        for (int c = 0; c < NUM_CLASSES; ++c) pw[c] += row[c];
    }
#pragma unroll
    for (int c = 0; c < NUM_CLASSES; ++c) {
        unsigned int v = pw[c];
        for (int off = 32; off > 0; off >>= 1)
            v += (unsigned int)__shfl_down((int)v, off, 64);
        pw[c] = v;
    }
    __shared__ unsigned int shw[4][NUM_CLASSES];
    __shared__ float fw[NUM_CLASSES];
    if (lane == 0) {
#pragma unroll
        for (int c = 0; c < NUM_CLASSES; ++c) shw[wave][c] = pw[c];
    }
    __syncthreads();
    if (threadIdx.x < NUM_CLASSES) {
        const int c = threadIdx.x;
        fw[c] = (float)(shw[0][c] + shw[1][c] + shw[2][c] + shw[3][c]);
    }
    __syncthreads();
    float w[NUM_CLASSES];
#pragma unroll
    for (int c = 0; c < NUM_CLASSES; ++c) w[c] = fw[c];

    // ---- phase 2: direct-load stream, barrier-free ----
    const float4* __restrict__ o4 = (const float4*)outputs;
    const int npairs = n >> 1;                    // 2^21
    const int stride = gridDim.x * blockDim.x;    // 524288 -> exactly 4 pairs/thread
    const int tid = blockIdx.x * blockDim.x + threadIdx.x;

    float sum_log = 0.f, sumsq = 0.f;
    if (npairs == 4 * stride) {
        // fast path: issue ALL 20 dwordx4 loads, pin them before any compute
        const float4* b0 = o4 + (size_t)(tid + 0 * stride) * 5;
        const float4* b1 = o4 + (size_t)(tid + 1 * stride) * 5;
        const float4* b2 = o4 + (size_t)(tid + 2 * stride) * 5;
        const float4* b3 = o4 + (size_t)(tid + 3 * stride) * 5;
        float4 g[20];
#pragma unroll
        for (int k = 0; k < 5; ++k) g[0 + k] = b0[k];
#pragma unroll
        for (int k = 0; k < 5; ++k) g[5 + k] = b1[k];
#pragma unroll
        for (int k = 0; k < 5; ++k) g[10 + k] = b2[k];
#pragma unroll
        for (int k = 0; k < 5; ++k) g[15 + k] = b3[k];
        __builtin_amdgcn_sched_barrier(0);  // loads issue before any compute
#pragma unroll
        for (int q = 0; q < 4; ++q)
            compute_from(g[5 * q], g[5 * q + 1], g[5 * q + 2], g[5 * q + 3], g[5 * q + 4],
                         w, sum_log, sumsq);
    } else {
        for (int p = tid; p < npairs; p += 2 * stride) {
            process_pair(o4, (size_t)p, w, sum_log, sumsq);
            const int p2 = p + stride;
            if (p2 < npairs) process_pair(o4, (size_t)p2, w, sum_log, sumsq);
        }
    }

    // ---- phase 3: block reduce, plain store of per-block partial ----
    for (int off = 32; off > 0; off >>= 1) {
        sum_log += __shfl_down(sum_log, off, 64);
        sumsq += __shfl_down(sumsq, off, 64);
    }
    __shared__ float s1[4], s2[4];
    if (lane == 0) { s1[wave] = sum_log; s2[wave] = sumsq; }
    __syncthreads();
    if (threadIdx.x == 0) {
        pacc[blockIdx.x] = make_float2(s1[0] + s1[1] + s1[2] + s1[3],
                                       s2[0] + s2[1] + s2[2] + s2[3]);
    }
}

__global__ void __launch_bounds__(256) finalize_kernel(const float2* __restrict__ pacc,
                                                       float* __restrict__ out, float fn) {
    float sum_log = 0.f, sumsq = 0.f;
    for (int i = threadIdx.x; i < B_BLOCKS; i += 256) {
        float2 v = pacc[i];
        sum_log += v.x;
        sumsq += v.y;
    }
    for (int off = 32; off > 0; off >>= 1) {
        sum_log += __shfl_down(sum_log, off, 64);
        sumsq += __shfl_down(sumsq, off, 64);
    }
    __shared__ float s1[4], s2[4];
    const int wave = threadIdx.x >> 6;
    if ((threadIdx.x & 63) == 0) { s1[wave] = sum_log; s2[wave] = sumsq; }
    __syncthreads();
    if (threadIdx.x == 0) {
        float t1 = s1[0] + s1[1] + s1[2] + s1[3];
        float t2 = s2[0] + s2[1] + s2[2] + s2[3];
        // mean(-log(nom/denom)) = 0.5*log(sumsq) + 0.5*log(N) - sum_log/N
        out[0] = 0.5f * logf(t2) + 0.5f * logf(fn) - t1 / fn;
    }
}

extern "C" void kernel_launch(void* const* d_in, const int* in_sizes, int n_in,
                              void* d_out, int out_size, void* d_ws, size_t ws_size,
                              hipStream_t stream) {
    const float* outputs = (const float*)d_in[0];
    const int* target = (const int*)d_in[1];
    const int n = in_sizes[1];

    unsigned int* pc = (unsigned int*)d_ws;
    float2* pacc = (float2*)((char*)d_ws + 20480);

    hist_kernel<<<A_BLOCKS, 256, 0, stream>>>(target, pc, n);
    main_kernel<<<B_BLOCKS, 256, 0, stream>>>(outputs, pc, pacc, n);
    finalize_kernel<<<1, 256, 0, stream>>>(pacc, (float*)d_out, (float)n);
}